// Round 9
// baseline (195.890 us; speedup 1.0000x reference)
//
#include <hip/hip_runtime.h>
#include <math.h>

namespace {

constexpr int B = 16, H = 512, W = 512;
constexpr int HWc = H * W;                 // 262144
constexpr size_t Nc = (size_t)B * HWc;     // 4194304

// wave owns 42 central cols (lanes 11..52) x 32 central rows.
// 13 strips x 16 bands x 16 images = 3328 waves, 4 waves/block.
constexpr int NSTRIP = 13, NBAND = 16;
constexpr int NWAVES = NSTRIP * NBAND * B;  // 3328
constexpr int WPI = NSTRIP * NBAND;         // 208 waves per image
constexpr int NBLK = NWAVES / 4;            // 832

typedef _Float16 h2 __attribute__((ext_vector_type(2)));

// DPP wave shifts: wave_shr:1 (0x138) / wave_shl:1 (0x130), old=self =>
// wave-edge lanes clamp to self (replicate). max/min symmetric so direction
// cannot matter. Packed halves (two rows) shift together across lanes.
// Per-pixel horizontal applications: 1 (boundary) + 10 (chain) = 11 = lane
// halo (central lanes 11..52).
template <int CTRL>
__device__ __forceinline__ int dpp_i(int i) {
  return __builtin_amdgcn_update_dpp(i, i, CTRL, 0xF, 0xF, false);
}
__device__ __forceinline__ h2 pkmax(h2 a, h2 b) {
  return __builtin_elementwise_max(a, b);
}
__device__ __forceinline__ h2 pkmin(h2 a, h2 b) {
  return __builtin_elementwise_min(a, b);
}
__device__ __forceinline__ h2 hmax3p(h2 v) {
  int iv = __builtin_bit_cast(int, v);
  h2 r1 = __builtin_bit_cast(h2, dpp_i<0x138>(iv));
  h2 r2 = __builtin_bit_cast(h2, dpp_i<0x130>(iv));
  return pkmax(pkmax(r1, v), r2);
}
__device__ __forceinline__ h2 hmin3p(h2 v) {
  int iv = __builtin_bit_cast(int, v);
  h2 r1 = __builtin_bit_cast(h2, dpp_i<0x138>(iv));
  h2 r2 = __builtin_bit_cast(h2, dpp_i<0x130>(iv));
  return pkmin(pkmin(r1, v), r2);
}
__device__ __forceinline__ h2 habs2(h2 v) {
  int iv = __builtin_bit_cast(int, v) & 0x7FFF7FFF;
  return __builtin_bit_cast(h2, iv);
}
// {lo.hi, hi.lo}: rows pair shifted by one row (v_alignbit_b32 shift 16)
__device__ __forceinline__ h2 algn(h2 hi, h2 lo) {
  unsigned r = __builtin_amdgcn_alignbit(__builtin_bit_cast(unsigned, hi),
                                         __builtin_bit_cast(unsigned, lo), 16);
  return __builtin_bit_cast(h2, r);
}

__device__ __forceinline__ float wave_sum(float v) {
#pragma unroll
  for (int off = 32; off > 0; off >>= 1) v += __shfl_down(v, off);
  return v;
}

__device__ __forceinline__ float block_reduce_256(float v, float* sm, int tid) {
  v = wave_sum(v);
  int lane = tid & 63, wid = tid >> 6;
  if (lane == 0) sm[wid] = v;
  __syncthreads();
  float r = 0.f;
  if (tid == 0) r = sm[0] + sm[1] + sm[2] + sm[3];
  __syncthreads();
  return r;
}

// in-place packed boundary: pairs k=1..26 become soft boundary of rows
// (2k, 2k+1); neighbors read as OLD values (ascending in-place is safe since
// a[k+1] is written at iteration k+1).
__device__ __forceinline__ void soft_boundary_p(h2 a[28]) {
  h2 oldp = a[0];
#pragma unroll
  for (int k = 1; k <= 26; ++k) {
    h2 oldk = a[k];
    h2 sdn = algn(oldk, oldp);      // rows (2k-1, 2k)
    h2 sup = algn(a[k + 1], oldk);  // rows (2k+1, 2k+2)
    h2 vmx = pkmax(pkmax(sdn, oldk), sup);
    h2 vmn = pkmin(pkmin(sdn, oldk), sup);
    a[k] = hmax3p(vmx) - hmin3p(vmn);
    oldp = oldk;
  }
}

// one 10-step dilation chain with per-step weighted |a - ref| accumulation
// over central pairs 6..21. Constant bounds k=1..26; stale creep 1 row/step:
// valid rows after step d = [d+2, 53-d] -> d=10 gives [12,43] = central.
__device__ __forceinline__ float run_chain_p(h2 a[28], const h2 ref[16]) {
  float acc = 0.f;
#pragma unroll
  for (int d = 1; d <= 10; ++d) {
    h2 oldp = a[0];
#pragma unroll
    for (int k = 1; k <= 26; ++k) {
      h2 oldk = a[k];
      h2 sdn = algn(oldk, oldp);
      h2 sup = algn(a[k + 1], oldk);
      a[k] = hmax3p(pkmax(pkmax(sdn, oldk), sup));
      oldp = oldk;
    }
    h2 a2;
    a2.x = (_Float16)0;
    a2.y = (_Float16)0;
#pragma unroll
    for (int j = 0; j < 16; ++j) a2 = a2 + habs2(a[j + 6] - ref[j]);
    acc += 0.1f * (float)d * ((float)a2.x + (float)a2.y);
  }
  return acc;
}

// ---------------- fused kernel ----------------
__global__ void __launch_bounds__(256, 4) fused_kernel(
    const float* __restrict__ logits, const int* __restrict__ target,
    float* __restrict__ bce_p, float* __restrict__ sp_p,
    float* __restrict__ st_p, float* __restrict__ spt_p,
    float* __restrict__ hd_p) {
  int tid = threadIdx.x;
  int lane = tid & 63;
  int wv = tid >> 6;
  int wid = blockIdx.x * 4 + wv;  // 0..3327
  int strip = wid % NSTRIP;
  int t2 = wid / NSTRIP;
  int band = t2 % NBAND;
  int img = t2 / NBAND;
  const float* L = logits + (size_t)img * HWc;
  const int* T = target + (size_t)img * HWc;
  int col = strip * 42 - 11 + lane;
  int colc = min(max(col, 0), W - 1);
  int y0 = band * 32;
  bool central = (lane >= 11 && lane <= 52 && col < W);

  // load 56-row window (y0-12 .. y0+43, clamped) as packed pairs; BCE/dice
  // partials on central pairs 6..21 (rows y0..y0+31, always in-image).
  h2 ap[28], at[28];
  float s_bce = 0.f, s_p = 0.f, s_t = 0.f, s_pt = 0.f;
#pragma unroll
  for (int k = 0; k < 28; ++k) {
    int r0 = min(max(y0 - 12 + 2 * k, 0), H - 1);
    int r1 = min(max(y0 - 11 + 2 * k, 0), H - 1);
    float x0 = L[r0 * W + colc], x1 = L[r1 * W + colc];
    float t0 = (float)T[r0 * W + colc], t1 = (float)T[r1 * W + colc];
    float p0 = 1.f / (1.f + expf(-x0));
    float p1 = 1.f / (1.f + expf(-x1));
    if (k >= 6 && k <= 21) {
      s_bce += fmaxf(x0, 0.f) - x0 * t0 + log1pf(expf(-fabsf(x0)));
      s_bce += fmaxf(x1, 0.f) - x1 * t1 + log1pf(expf(-fabsf(x1)));
      s_p += p0 + p1;
      s_t += t0 + t1;
      s_pt += p0 * t0 + p1 * t1;
    }
    h2 pv;
    pv.x = (_Float16)p0;
    pv.y = (_Float16)p1;
    ap[k] = pv;
    h2 tv;
    tv.x = (_Float16)t0;
    tv.y = (_Float16)t1;
    at[k] = tv;
  }

  soft_boundary_p(ap);
  soft_boundary_p(at);

  // snapshot pred boundary central pairs (at stays intact through chain A)
  h2 op[16];
#pragma unroll
  for (int j = 0; j < 16; ++j) op[j] = ap[j + 6];

  float acc = run_chain_p(ap, &at[6]);  // pred chain vs gt boundary
  acc += run_chain_p(at, op);           // gt chain vs pred boundary

  if (!central) {
    acc = 0.f;
    s_bce = 0.f;
    s_p = 0.f;
    s_t = 0.f;
    s_pt = 0.f;
  }
  s_bce = wave_sum(s_bce);
  s_p = wave_sum(s_p);
  s_t = wave_sum(s_t);
  s_pt = wave_sum(s_pt);
  acc = wave_sum(acc);
  if (lane == 0) {
    bce_p[wid] = s_bce;
    sp_p[wid] = s_p;
    st_p[wid] = s_t;
    spt_p[wid] = s_pt;
    hd_p[wid] = acc;
  }
}

// ---------------- finalize ----------------
__global__ void finalize_kernel(const float* __restrict__ bce_p,
                                const float* __restrict__ sp_p,
                                const float* __restrict__ st_p,
                                const float* __restrict__ spt_p,
                                const float* __restrict__ hd_p,
                                float* __restrict__ out) {
  __shared__ float smr[4];
  __shared__ float simg[16][16][3];
  __shared__ double img_terms[16][2];
  int tid = threadIdx.x;

  float s = 0.f;
  for (int i = tid; i < NWAVES; i += 256) s += bce_p[i];
  float bce_sum = block_reduce_256(s, smr, tid);

  s = 0.f;
  for (int i = tid; i < NWAVES; i += 256) s += hd_p[i];
  float hd_sum = block_reduce_256(s, smr, tid);

  // per-image sums: 16 threads per image over its 208 partials
  int im = tid >> 4, j = tid & 15;
  float sp = 0.f, st = 0.f, spt = 0.f;
  for (int k = j; k < WPI; k += 16) {
    int idx = im * WPI + k;
    sp += sp_p[idx];
    st += st_p[idx];
    spt += spt_p[idx];
  }
  simg[im][j][0] = sp;
  simg[im][j][1] = st;
  simg[im][j][2] = spt;
  __syncthreads();
  if (tid < 16) {
    double dsp = 0.0, dst = 0.0, dspt = 0.0;
    for (int j2 = 0; j2 < 16; ++j2) {
      dsp += (double)simg[tid][j2][0];
      dst += (double)simg[tid][j2][1];
      dspt += (double)simg[tid][j2][2];
    }
    double dice = (2.0 * dspt + 1e-6) / (dsp + dst + 1e-6 + 1e-7);
    double tv = (dspt + 1e-6) /
                (dspt + 0.7 * (dsp - dspt) + 0.3 * (dst - dspt) + 1e-6 + 1e-7);
    img_terms[tid][0] = 1.0 - dice;
    img_terms[tid][1] = pow(1.0 - tv, 0.75);
  }
  __syncthreads();
  if (tid == 0) {
    const double Nd = (double)Nc;
    double dice_l = 0.0, ft_l = 0.0;
    for (int i = 0; i < 16; ++i) {
      dice_l += img_terms[i][0];
      ft_l += img_terms[i][1];
    }
    dice_l /= 16.0;
    ft_l /= 16.0;
    double bce = (double)bce_sum / Nd;
    double hd = ((double)hd_sum / Nd) / (5.5 + 1e-8);
    out[0] = (float)(bce + dice_l + ft_l + 0.1 * hd);
  }
}

}  // namespace

extern "C" void kernel_launch(void* const* d_in, const int* in_sizes, int n_in,
                              void* d_out, int out_size, void* d_ws,
                              size_t ws_size, hipStream_t stream) {
  const float* logits = (const float*)d_in[0];
  const int* target = (const int*)d_in[1];
  float* out = (float*)d_out;

  float* part = (float*)d_ws;
  float* bce_p = part;                // NWAVES
  float* sp_p = part + NWAVES;        // NWAVES
  float* st_p = part + 2 * NWAVES;    // NWAVES
  float* spt_p = part + 3 * NWAVES;   // NWAVES
  float* hd_p = part + 4 * NWAVES;    // NWAVES

  fused_kernel<<<dim3(NBLK), dim3(256), 0, stream>>>(logits, target, bce_p,
                                                     sp_p, st_p, spt_p, hd_p);
  finalize_kernel<<<1, 256, 0, stream>>>(bce_p, sp_p, st_p, spt_p, hd_p, out);
}